// Round 11
// baseline (1407.311 us; speedup 1.0000x reference)
//
#include <hip/hip_runtime.h>
#include <hip/hip_fp16.h>

// SequentialChart: ops < START(256) => steps independent. Algebraic cut:
// PL[b,op]=U_left@h(b,op), PR[b,op]=U_right@h(b,op) (16x fewer FLOPs),
// preact = PL[opL]+PR[opR] (bias folded into PL at GEMM epilogue).
// log2e folded into U/bias at cvt time: gates use raw v_exp (exp2).
// GEMM: 256x256 8-phase schedule, BK=64, 8 waves, 128KB LDS, merged over
// all bg (1280 blocks = 5 exact rounds). P stores CACHED (re-read by fused).
// k_fused v5: online softmax + COLUMN SUB-PHASING with full MLP:
// Phase A = all 8 rows cols [0,512) (pending h in 32 regs, pending c in the
// wave's 8KB slice of the merge-LDS, aliased); Phase B = cols [512,1024),
// completes e,w and weights pending+live. Per-XCD active P footprint
// 3MB < 4MB L2 (round-5 evidence: 343MB FETCH when sub-phased).

typedef unsigned int u32;
typedef unsigned short u16;
typedef __attribute__((ext_vector_type(8))) short short8;
typedef __attribute__((ext_vector_type(4))) float f32x4;
typedef __attribute__((ext_vector_type(4))) u16 u16x4;
typedef _Float16 h8 __attribute__((ext_vector_type(8)));
typedef _Float16 h2v __attribute__((ext_vector_type(2)));
typedef _Float16 h4v __attribute__((ext_vector_type(4)));

#define CHART_ROWS 384
#define L2E 1.4426950408889634f

__device__ __forceinline__ u16 f2bf(float f) {           // fp32 -> bf16 RNE
  u32 u = __float_as_uint(f);
  u32 r = u + 0x7fffu + ((u >> 16) & 1u);
  return (u16)(r >> 16);
}

// packed f16 exp2 / rcp via HIP half2 intrinsics (lower to v_exp_f16/v_rcp_f16)
__device__ __forceinline__ h2v pk_exp2(h2v x) {
  __half2 t = *(__half2*)&x;
  t = h2exp2(t);
  return *(h2v*)&t;
}
__device__ __forceinline__ h2v pk_rcp(h2v x) {
  __half2 t = *(__half2*)&x;
  t = h2rcp(t);
  return *(h2v*)&t;
}

#if __has_builtin(__builtin_amdgcn_fdot2)
__device__ __forceinline__ float fdot2a(h2v a, h2v b, float c) {
  return __builtin_amdgcn_fdot2(a, b, c, false);
}
#else
__device__ __forceinline__ float fdot2a(h2v a, h2v b, float c) {
  return c + (float)a[0] * (float)b[0] + (float)a[1] * (float)b[1];
}
#endif

__device__ __forceinline__ void async16(const void* g, void* l) {
  __builtin_amdgcn_global_load_lds((const __attribute__((address_space(1))) u32*)g,
                                   (__attribute__((address_space(3))) u32*)l, 16, 0, 0);
}

#define BAR() __builtin_amdgcn_s_barrier()
#define VMCNT4 asm volatile("s_waitcnt vmcnt(4)" ::: "memory")
#define VMCNT0 asm volatile("s_waitcnt vmcnt(0)" ::: "memory")

// ---- merged cvt: blocks [0,10240): U fp32->bf16 scaled; blocks [10240,18432):
// chart split (h->chb bf16, c->chc f16, rows<256 passthrough to out, nt)
__global__ void k_cvt(const f32x4* __restrict__ U4, u16* __restrict__ Ubf,
                      const float* __restrict__ chart, u16* __restrict__ chb,
                      _Float16* __restrict__ chc, float* __restrict__ out) {
  if (blockIdx.x < 10240) {
    int i = blockIdx.x * 256 + threadIdx.x;          // 2,621,440 threads
    int row = i >> 9;                                // 512 float4 per 2048-col row
    float sc = (row < 4096) ? -L2E : (2.0f * L2E);
    f32x4 v = U4[i];
    u16x4 o = {f2bf(v[0] * sc), f2bf(v[1] * sc), f2bf(v[2] * sc), f2bf(v[3] * sc)};
    *(u16x4*)(Ubf + (size_t)i * 4) = o;
  } else {
    int i = (blockIdx.x - 10240) * 256 + threadIdx.x;   // 2,097,152 threads
    int row = i >> 8;                 // b*256 + op, < 8192
    int k4 = (i & 255) * 4;
    int b = row >> 8, op = row & 255;
    const size_t base = (size_t)(b * CHART_ROWS + op) * 2048;
    const f32x4 vh = *(const f32x4*)(chart + base + 1024 + k4);
    const f32x4 vc = *(const f32x4*)(chart + base + k4);
    u16x4 oh = {f2bf(vh[0]), f2bf(vh[1]), f2bf(vh[2]), f2bf(vh[3])};
    h4v oc = {(_Float16)vc[0], (_Float16)vc[1], (_Float16)vc[2], (_Float16)vc[3]};
    *(u16x4*)(chb + (size_t)row * 1024 + k4) = oh;
    *(h4v*)(chc + (size_t)row * 1024 + k4) = oc;
    __builtin_nontemporal_store(vc, (f32x4*)(out + base + k4));
    __builtin_nontemporal_store(vh, (f32x4*)(out + base + 1024 + k4));
  }
}

// ---- P[bgh][2048 rows][5120] = chb-rows @ U-half (+bias*scale on half0)
// 256x256 tile, BK=64, 8 waves (2Mx4N), 8-phase double-buffered pipeline.
#define LOAD_A(BUFO, MH) do { \
  _Pragma("unroll") \
  for (int i_ = 0; i_ < 4; ++i_) { \
    a[0][i_] = *(const short8*)(As + (BUFO) + am + (MH)*4096 + i_*1024 + sl0); \
    a[1][i_] = *(const short8*)(As + (BUFO) + am + (MH)*4096 + i_*1024 + sl1); \
  } } while (0)

#define LOAD_B(BUFO, NH, BR) do { \
  _Pragma("unroll") \
  for (int j_ = 0; j_ < 2; ++j_) { \
    BR[0][j_] = *(const short8*)(Bs + (BUFO) + bm + (NH)*2048 + j_*1024 + sl0); \
    BR[1][j_] = *(const short8*)(Bs + (BUFO) + bm + (NH)*2048 + j_*1024 + sl1); \
  } } while (0)

#define MFMA_Q(MH, NH, BR) do { \
  __builtin_amdgcn_s_setprio(1); \
  _Pragma("unroll") \
  for (int kk_ = 0; kk_ < 2; ++kk_) \
    _Pragma("unroll") \
    for (int i_ = 0; i_ < 4; ++i_) \
      _Pragma("unroll") \
      for (int j_ = 0; j_ < 2; ++j_) \
        acc[(MH)*4+i_][(NH)*2+j_] = __builtin_amdgcn_mfma_f32_16x16x32_bf16( \
            a[kk_][i_], BR[kk_][j_], acc[(MH)*4+i_][(NH)*2+j_], 0, 0, 0); \
  __builtin_amdgcn_s_setprio(0); } while (0)

__global__ __launch_bounds__(512, 2) void k_gemm_p(
    const u16* __restrict__ chb, const u16* __restrict__ Ubf,
    const float* __restrict__ bias, _Float16* __restrict__ P, int bgh_base)
{
  __shared__ u16 As[2 * 256 * 64];   // 64 KB: two K-tile buffers (halves stacked)
  __shared__ u16 Bs[2 * 256 * 64];   // 64 KB

  const int tid = threadIdx.x;
  const int wid = tid >> 6, lane = tid & 63;
  const int lane15 = lane & 15, quad = lane >> 4;
  const int wr = wid >> 2, wc = wid & 3;

  // XCD-aware bijective swizzle (nwg % 8 == 0 in both launch shapes)
  const int nwg = gridDim.x * gridDim.y;
  const int flat = blockIdx.y * gridDim.x + blockIdx.x;
  const int swz = (flat & 7) * (nwg >> 3) + (flat >> 3);
  const int bx = swz % 20;                 // N tile (0..19)
  const int by = swz / 20;
  const int bghl = by >> 3;                // local bgh slab in P
  const int bgh = bgh_base + bghl;
  const int bg = bgh >> 1, uhalf = bgh & 1;
  const int mtile = by & 7;

  // staging: half-tile = 128 rows x 64 cols bf16 = 16KB = 2 rounds x 512 thr x 16B
  const u16* aSrc[2]; const u16* bSrc[2]; int dOff[2];
#pragma unroll
  for (int rnd = 0; rnd < 2; ++rnd) {
    int idx = rnd * 512 + tid;
    int r = idx >> 3, s = idx & 7, c = s ^ (r & 7);
    aSrc[rnd] = chb + (size_t)(bg * 2048 + mtile * 256 + r) * 1024 + c * 8;
    bSrc[rnd] = Ubf + (size_t)(bx * 256 + r) * 2048 + uhalf * 1024 + c * 8;
    dOff[rnd] = idx * 8;                   // u16 units
  }
  auto STAGE_A = [&](int buf, int h, int T) {
#pragma unroll
    for (int rnd = 0; rnd < 2; ++rnd)
      async16(aSrc[rnd] + (size_t)h * 131072 + T * 64,
              As + buf * 16384 + h * 8192 + dOff[rnd]);
  };
  auto STAGE_B = [&](int buf, int h, int T) {
#pragma unroll
    for (int rnd = 0; rnd < 2; ++rnd)
      async16(bSrc[rnd] + (size_t)h * 262144 + T * 64,
              Bs + buf * 16384 + h * 8192 + dOff[rnd]);
  };

  // fragment read bases; m&7 == g&7 == lane15&7 (all tile offsets are mult of 8)
  const int sl0 = ((0 * 4 + quad) ^ (lane15 & 7)) * 8;   // kk=0 slot
  const int sl1 = ((1 * 4 + quad) ^ (lane15 & 7)) * 8;   // kk=1 slot
  const int am = (wr * 128 + lane15) * 64;   // + mh*4096 + i*1024
  const int bm = (wc * 64 + lane15) * 64;    // + nh*2048 + j*1024

  f32x4 acc[8][4];
#pragma unroll
  for (int m_ = 0; m_ < 8; ++m_)
#pragma unroll
    for (int n_ = 0; n_ < 4; ++n_) acc[m_][n_] = (f32x4){0.f, 0.f, 0.f, 0.f};

  short8 a[2][4], b0[2][2], b1[2][2];

  // prologue: tile0 fully + tile1 B-halves; tile1 A staged in iter0 p1/p2
  STAGE_B(0, 0, 0); STAGE_B(0, 1, 0); STAGE_A(0, 0, 0); STAGE_A(0, 1, 0);
  STAGE_B(1, 0, 1); STAGE_B(1, 1, 1);
  VMCNT4;                                  // tile0 landed (tile1-B in flight)
  BAR();

  for (int it = 0; it < 8; ++it) {
    const int T1 = 2 * it + 1, T2 = 2 * it + 2, T3 = 2 * it + 3;
    const bool e2 = (T2 < 16), e3 = (T3 < 16);
    // ---- phases 1-4: tile 2it from buf0 ----
    LOAD_A(0, 0); LOAD_B(0, 0, b0);
    STAGE_A(1, 0, T1);
    BAR(); MFMA_Q(0, 0, b0); BAR();

    LOAD_B(0, 1, b1);
    STAGE_A(1, 1, T1);
    BAR(); MFMA_Q(0, 1, b1); BAR();

    LOAD_A(0, 1);
    if (e2) STAGE_B(0, 0, T2);             // buf0 B free after phase 2
    BAR(); MFMA_Q(1, 0, b0); BAR();

    if (e2) STAGE_B(0, 1, T2);
    BAR(); MFMA_Q(1, 1, b1);
    if (e2) { VMCNT4; } else { VMCNT0; }   // tile 2it+1 fully landed
    BAR();
    // ---- phases 5-8: tile 2it+1 from buf1 ----
    LOAD_A(16384, 0); LOAD_B(16384, 0, b0);
    if (e2) STAGE_A(0, 0, T2);             // buf0 A free after phase 3
    BAR(); MFMA_Q(0, 0, b0); BAR();

    LOAD_B(16384, 1, b1);
    if (e2) STAGE_A(0, 1, T2);
    BAR(); MFMA_Q(0, 1, b1); BAR();

    LOAD_A(16384, 1);
    if (e3) STAGE_B(1, 0, T3);             // buf1 B free after phase 6
    BAR(); MFMA_Q(1, 0, b0); BAR();

    if (e3) STAGE_B(1, 1, T3);
    BAR(); MFMA_Q(1, 1, b1);
    if (e3) { VMCNT4; }                    // tile 2it+2 fully landed
    BAR();
  }

  // epilogue: bias (half0 only, pre-scaled) + fp16 CACHED store (P is
  // re-read ~16x by k_fused -- keep it in L2/LLC)
  float bb[4];
#pragma unroll
  for (int nt = 0; nt < 4; ++nt) {
    int g = bx * 256 + wc * 64 + nt * 16 + lane15;
    float sc = (g < 4096) ? -L2E : (2.0f * L2E);
    bb[nt] = (uhalf == 0) ? bias[g] * sc : 0.f;
  }
  _Float16* Pb = P + ((size_t)bghl * 2048 + mtile * 256 + wr * 128) * 5120
               + bx * 256 + wc * 64;
#pragma unroll
  for (int mt = 0; mt < 8; ++mt)
#pragma unroll
    for (int rg = 0; rg < 4; ++rg) {
      _Float16* pr = Pb + (size_t)(mt * 16 + quad * 4 + rg) * 5120;
#pragma unroll
      for (int nt = 0; nt < 4; ++nt)
        pr[nt * 16 + lane15] = (_Float16)(acc[mt][nt][rg] + bb[nt]);
    }
}

// ---- fused v5: sub-phased online softmax-combine with full MLP ----
// 4 waves x 8 rows. Phase A: all rows, cols [0,512); pending h in regs,
// pending c (f16) in the wave's 8KB slice of rS (aliased; merge writes
// happen only after all pending reads -- wave-private, no barrier needed).
// Phase B: all rows, cols [512,1024); completes dot/nn -> e,w; weights
// live + pending into Sc/Sh (f32). Then 4-wave merge through rS.
__global__ __launch_bounds__(256, 2) void k_fused(
    const _Float16* __restrict__ chc, const _Float16* __restrict__ P,
    const int* __restrict__ ops, const float* __restrict__ eu,
    float* __restrict__ out, int bg0)
{
  __shared__ float rS[4 * 2048];   // 32 KB; phase A/B: per-wave cPend slices
  __shared__ float sS[4];

  const int tid = threadIdx.x;
  const int wave = tid >> 6, lane = tid & 63;
  const int flat = blockIdx.x;
  const int b_local = flat & 7;     // XCD-affine: same-XCD blocks share b
  const int idx = flat >> 3;
  const int step = idx & 127;
  const int bgl = idx >> 7;         // slab index within P
  const int b = (bg0 + bgl) * 8 + b_local;
  const size_t HSLAB = (size_t)2048 * 5120;
  const _Float16* Pl = P + (size_t)(2 * bgl) * HSLAB;
  _Float16* cP = (_Float16*)rS + wave * 4096;   // wave-private 8KB = [8 rows][512] f16

  // energy_u: f32 for unorm, f16 pairs for fdot2
  float uf[2][8];
#pragma unroll
  for (int sub = 0; sub < 2; ++sub) {
    *(f32x4*)&uf[sub][0] = *(const f32x4*)(eu + sub * 512 + lane * 8);
    *(f32x4*)&uf[sub][4] = *(const f32x4*)(eu + sub * 512 + lane * 8 + 4);
  }
  float part = 0.f;
#pragma unroll
  for (int sub = 0; sub < 2; ++sub)
#pragma unroll
    for (int j = 0; j < 8; ++j) part += uf[sub][j] * uf[sub][j];
#pragma unroll
  for (int m = 1; m < 64; m <<= 1) part += __shfl_xor(part, m, 64);
  const float unorm = fmaxf(sqrtf(part), 1e-8f);
  h2v uu2[2][4];
#pragma unroll
  for (int sub = 0; sub < 2; ++sub)
#pragma unroll
    for (int p = 0; p < 4; ++p)
      uu2[sub][p] = (h2v){(_Float16)uf[sub][2 * p], (_Float16)uf[sub][2 * p + 1]};

  const h2v one2 = {(_Float16)1.0f, (_Float16)1.0f};
  const h2v m2h  = {(_Float16)(-2.0f), (_Float16)(-2.0f)};
  const h2v k2c  = {(_Float16)(2.0f * L2E), (_Float16)(2.0f * L2E)};

  float Sc[2][8], Sh[2][8];
#pragma unroll
  for (int sub = 0; sub < 2; ++sub)
#pragma unroll
    for (int j = 0; j < 8; ++j) { Sc[sub][j] = 0.f; Sh[sub][j] = 0.f; }
  float Ssum = 0.f;

  h2v hP[8][4];                 // pending sub0 h (32 VGPRs)
  float dotP[8], nnP[8];        // partial reductions (16 VGPRs)

  // ---- Phase A: all 8 rows, cols [0,512) ----
  for (int rr = 0; rr < 8; ++rr) {
    const int a = wave * 8 + rr;
    const long opflat = (((long)step * 32 + b) * 32 + a) * 2;
    const int opL = ops[opflat], opR = ops[opflat + 1];
    const int cb = lane * 8;
    const _Float16* PLp = Pl + (size_t)(b_local * 256 + opL) * 5120 + cb;
    const _Float16* PRp = Pl + HSLAB + (size_t)(b_local * 256 + opR) * 5120 + cb;
    h2v pr2[5][4];
#pragma unroll
    for (int q = 0; q < 5; ++q) {
      h8 t8 = *(const h8*)(PLp + q * 1024) + *(const h8*)(PRp + q * 1024);
      *(h8*)&pr2[q][0] = t8;
    }
    h2v cl2[4], cr2[4];
    *(h8*)&cl2[0] = *(const h8*)(chc + (size_t)(b * 256 + opL) * 1024 + cb);
    *(h8*)&cr2[0] = *(const h8*)(chc + (size_t)(b * 256 + opR) * 1024 + cb);
    float dot = 0.f, nn = 0.f;
    h2v cv4[4];
#pragma unroll
    for (int p = 0; p < 4; ++p) {
      h2v sI = pk_rcp(one2 + pk_exp2(pr2[0][p]));   // args pre-scaled -log2e
      h2v sL = pk_rcp(one2 + pk_exp2(pr2[1][p]));
      h2v sR = pk_rcp(one2 + pk_exp2(pr2[2][p]));
      h2v sO = pk_rcp(one2 + pk_exp2(pr2[3][p]));
      h2v rU = pk_rcp(one2 + pk_exp2(pr2[4][p]));   // pre-scaled +2log2e
      h2v tU = one2 + m2h * rU;                     // tanh(u)
      h2v c2 = sL * cl2[p] + sR * cr2[p] + sI * tU;
      h2v rC = pk_rcp(one2 + pk_exp2(c2 * k2c));
      h2v tC = one2 + m2h * rC;                     // tanh(c)
      h2v hx = sO * tC;
      cv4[p] = c2; hP[rr][p] = hx;
      dot = fdot2a(hx, uu2[0][p], dot);
      nn  = fdot2a(hx, hx, nn);
    }
    *(h8*)(cP + rr * 512 + lane * 8) = *(h8*)&cv4[0];   // pending c -> LDS
    dotP[rr] = dot; nnP[rr] = nn;
  }

  // ---- Phase B: all 8 rows, cols [512,1024); complete + weight ----
  for (int rr = 0; rr < 8; ++rr) {
    const int a = wave * 8 + rr;
    const long opflat = (((long)step * 32 + b) * 32 + a) * 2;
    const int opL = ops[opflat], opR = ops[opflat + 1];
    const int cb = 512 + lane * 8;
    const _Float16* PLp = Pl + (size_t)(b_local * 256 + opL) * 5120 + cb;
    const _Float16* PRp = Pl + HSLAB + (size_t)(b_local * 256 + opR) * 5120 + cb;
    h2v pr2[5][4];
#pragma unroll
    for (int q = 0; q < 5; ++q) {
      h8 t8 = *(const h8*)(PLp + q * 1024) + *(const h8*)(PRp + q * 1024);
      *(h8*)&pr2[q][0] = t8;
    }
    h2v cl2[4], cr2[4];
    *(h8*)&cl2[0] = *(const h8*)(chc + (size_t)(b * 256 + opL) * 1024 + cb);
    *(h8*)&cr2[0] = *(const h8*)(chc + (size_t)(b * 256 + opR) * 1024 + cb);
    float dot = dotP[rr], nn = nnP[rr];
    h2v cv1[4], hv1[4];
#pragma unroll
    for (int p = 0; p < 4; ++p) {
      h2v sI = pk_rcp(one2 + pk_exp2(pr2[0][p]));
      h2v sL = pk_rcp(one2 + pk_exp2(pr2[1][p]));
      h2v sR = pk_rcp(one2 + pk_exp2(pr2[2][p]));
      h2v sO = pk_rcp(one2 + pk_exp2(pr2[3][p]));
      h2v rU = pk_rcp(one2 + pk_exp2(pr2[4][p]));
      h2v tU = one2 + m2h * rU;
      h2v c2 = sL * cl2[p] + sR * cr2[p] + sI * tU;
      h2v rC = pk_rcp(one2 + pk_exp2(c2 * k2c));
      h2v tC = one2 + m2h * rC;
      h2v hx = sO * tC;
      cv1[p] = c2; hv1[p] = hx;
      dot = fdot2a(hx, uu2[1][p], dot);
      nn  = fdot2a(hx, hx, nn);
    }
#pragma unroll
    for (int m = 1; m < 64; m <<= 1) {
      dot += __shfl_xor(dot, m, 64);
      nn  += __shfl_xor(nn, m, 64);
    }
    const float e = dot / (unorm * fmaxf(sqrtf(nn), 1e-8f));
    const float w = __builtin_amdgcn_exp2f(e * L2E);        // exp(e), e in [-1,1]
    Ssum += w;
    h2v cp4[4];
    *(h8*)&cp4[0] = *(const h8*)(cP + rr * 512 + lane * 8);  // pending c back
#pragma unroll
    for (int p = 0; p < 4; ++p) {
      Sc[1][2 * p]     += w * (float)cv1[p][0];
      Sc[1][2 * p + 1] += w * (float)cv1[p][1];
      Sh[1][2 * p]     += w * (float)hv1[p][0];
      Sh[1][2 * p + 1] += w * (float)hv1[p][1];
      Sc[0][2 * p]     += w * (float)cp4[p][0];
      Sc[0][2 * p + 1] += w * (float)cp4[p][1];
      Sh[0][2 * p]     += w * (float)hP[rr][p][0];
      Sh[0][2 * p + 1] += w * (float)hP[rr][p][1];
    }
  }

  // ---- 4-wave merge through rS (cPend fully consumed; wave-private alias) ----
  if (lane == 0) sS[wave] = Ssum;
#pragma unroll
  for (int sub = 0; sub < 2; ++sub) {
    const int cb = sub * 512 + lane * 8;
    *(f32x4*)&rS[wave * 2048 + cb]            = *(f32x4*)&Sc[sub][0];
    *(f32x4*)&rS[wave * 2048 + cb + 4]        = *(f32x4*)&Sc[sub][4];
    *(f32x4*)&rS[wave * 2048 + 1024 + cb]     = *(f32x4*)&Sh[sub][0];
    *(f32x4*)&rS[wave * 2048 + 1024 + cb + 4] = *(f32x4*)&Sh[sub][4];
  }
  __syncthreads();

  const float inv = 1.0f / (sS[0] + sS[1] + sS[2] + sS[3]);
  float* orow = out + ((size_t)b * CHART_ROWS + 256 + step) * 2048;
#pragma unroll
  for (int half = 0; half < 2; ++half) {     // 0: c cols, 1: h cols
#pragma unroll
    for (int sub = 0; sub < 2; ++sub) {
      const int cb = sub * 512 + lane * 8;
      const int off = half * 1024 + cb;
      float s0 = 0.f, s1 = 0.f, s2 = 0.f, s3 = 0.f;
      float s4 = 0.f, s5 = 0.f, s6 = 0.f, s7 = 0.f;
#pragma unroll
      for (int w8 = 0; w8 < 4; ++w8) {
        const f32x4 v0 = *(const f32x4*)&rS[w8 * 2048 + off];
        const f32x4 v1 = *(const f32x4*)&rS[w8 * 2048 + off + 4];
        s0 += v0[0]; s1 += v0[1]; s2 += v0[2]; s3 += v0[3];
        s4 += v1[0]; s5 += v1[1]; s6 += v1[2]; s7 += v1[3];
      }
      __builtin_nontemporal_store(
          (f32x4){s0 * inv, s1 * inv, s2 * inv, s3 * inv}, (f32x4*)(orow + off));
      __builtin_nontemporal_store(
          (f32x4){s4 * inv, s5 * inv, s6 * inv, s7 * inv}, (f32x4*)(orow + off + 4));
    }
  }
}

extern "C" void kernel_launch(void* const* d_in, const int* in_sizes, int n_in,
                              void* d_out, int out_size, void* d_ws, size_t ws_size,
                              hipStream_t stream) {
  (void)in_sizes; (void)n_in; (void)out_size;
  const float* chart = (const float*)d_in[0];
  const int*   ops   = (const int*)d_in[1];
  // d_in[2] = start_index (256, hard-coded)
  const float* U     = (const float*)d_in[3];
  const float* bias  = (const float*)d_in[4];
  const float* eu    = (const float*)d_in[5];
  float* out = (float*)d_out;
  char* ws = (char*)d_ws;

  u16*      Ubf = (u16*)ws;                       // 20,971,520 B
  u16*      chb = (u16*)(ws + 20971520);          // 16,777,216 B
  _Float16* chc = (_Float16*)(ws + 37748736);     // 16,777,216 B
  _Float16* P   = (_Float16*)(ws + 54525952);     // big: 167,772,160 B (8 slabs)
                                                  // small: 41,943,040 B (2 slabs)
  const size_t SLAB = (size_t)2048 * 5120;        // _Float16 per slab
  const bool big = ws_size >= (size_t)54525952 + 8 * SLAB * 2;

  k_cvt<<<18432, 256, 0, stream>>>((const f32x4*)U, Ubf, chart, chb, chc, out);

  if (big) {
    // 1280 tiles (20 bx x 8 bgh x 8 mt), 5 exact rounds of 256 blocks
    k_gemm_p<<<dim3(20, 64), 512, 0, stream>>>(chb, Ubf, bias, P, 0);
    // single fused dispatch over all bg (4096 blocks x 256 thr)
    k_fused<<<4096, 256, 0, stream>>>(chc, P, ops, eu, out, 0);
  } else {
    for (int bg = 0; bg < 4; ++bg) {
      k_gemm_p<<<dim3(20, 16), 512, 0, stream>>>(chb, Ubf, bias, P, 2 * bg);
      k_fused<<<1024, 256, 0, stream>>>(chc, P, ops, eu, out, bg);
    }
  }
}

// Round 12
// 570.817 us; speedup vs baseline: 2.4654x; 2.4654x over previous
//
#include <hip/hip_runtime.h>
#include <hip/hip_fp16.h>

// SequentialChart: ops < START(256) => steps independent. Algebraic cut:
// PL[b,op]=U_left@h(b,op), PR[b,op]=U_right@h(b,op) (16x fewer FLOPs),
// preact = PL[opL]+PR[opR] (bias folded into PL at GEMM epilogue).
// log2e folded into U/bias at cvt time: gates use raw v_exp (exp2).
// GEMM: 256x256 8-phase schedule, BK=64, 8 waves, 128KB LDS, merged over
// all bg (1280 blocks). P stores CACHED (re-read ~16x by k_fused).
// k_fused v6: online softmax + column sub-phasing, FULLY UNROLLED row
// loops (v5's rolled loops put hP[rr]/dotP[rr] in scratch -> 4.5x
// regression; FETCH=410MB proved the phasing itself works). Phase A:
// all 8 rows cols [0,512), pending h in 32 static regs + pending c in
// the wave's 8KB LDS slice (aliased with merge buffer). Phase B: cols
// [512,1024) -> e,w -> weight pending+live. Sc/Sh declared after Phase
// A to keep Phase-A register liveness ~70 (fits 128 cap, no spill).

typedef unsigned int u32;
typedef unsigned short u16;
typedef __attribute__((ext_vector_type(8))) short short8;
typedef __attribute__((ext_vector_type(4))) float f32x4;
typedef __attribute__((ext_vector_type(4))) u16 u16x4;
typedef _Float16 h8 __attribute__((ext_vector_type(8)));
typedef _Float16 h2v __attribute__((ext_vector_type(2)));
typedef _Float16 h4v __attribute__((ext_vector_type(4)));

#define CHART_ROWS 384
#define L2E 1.4426950408889634f

__device__ __forceinline__ u16 f2bf(float f) {           // fp32 -> bf16 RNE
  u32 u = __float_as_uint(f);
  u32 r = u + 0x7fffu + ((u >> 16) & 1u);
  return (u16)(r >> 16);
}

// packed f16 exp2 / rcp via HIP half2 intrinsics (lower to v_exp_f16/v_rcp_f16)
__device__ __forceinline__ h2v pk_exp2(h2v x) {
  __half2 t = *(__half2*)&x;
  t = h2exp2(t);
  return *(h2v*)&t;
}
__device__ __forceinline__ h2v pk_rcp(h2v x) {
  __half2 t = *(__half2*)&x;
  t = h2rcp(t);
  return *(h2v*)&t;
}

#if __has_builtin(__builtin_amdgcn_fdot2)
__device__ __forceinline__ float fdot2a(h2v a, h2v b, float c) {
  return __builtin_amdgcn_fdot2(a, b, c, false);
}
#else
__device__ __forceinline__ float fdot2a(h2v a, h2v b, float c) {
  return c + (float)a[0] * (float)b[0] + (float)a[1] * (float)b[1];
}
#endif

__device__ __forceinline__ void async16(const void* g, void* l) {
  __builtin_amdgcn_global_load_lds((const __attribute__((address_space(1))) u32*)g,
                                   (__attribute__((address_space(3))) u32*)l, 16, 0, 0);
}

#define BAR() __builtin_amdgcn_s_barrier()
#define VMCNT4 asm volatile("s_waitcnt vmcnt(4)" ::: "memory")
#define VMCNT0 asm volatile("s_waitcnt vmcnt(0)" ::: "memory")

// ---- merged cvt: blocks [0,10240): U fp32->bf16 scaled; blocks [10240,18432):
// chart split (h->chb bf16, c->chc f16, rows<256 passthrough to out, nt)
__global__ void k_cvt(const f32x4* __restrict__ U4, u16* __restrict__ Ubf,
                      const float* __restrict__ chart, u16* __restrict__ chb,
                      _Float16* __restrict__ chc, float* __restrict__ out) {
  if (blockIdx.x < 10240) {
    int i = blockIdx.x * 256 + threadIdx.x;          // 2,621,440 threads
    int row = i >> 9;                                // 512 float4 per 2048-col row
    float sc = (row < 4096) ? -L2E : (2.0f * L2E);
    f32x4 v = U4[i];
    u16x4 o = {f2bf(v[0] * sc), f2bf(v[1] * sc), f2bf(v[2] * sc), f2bf(v[3] * sc)};
    *(u16x4*)(Ubf + (size_t)i * 4) = o;
  } else {
    int i = (blockIdx.x - 10240) * 256 + threadIdx.x;   // 2,097,152 threads
    int row = i >> 8;                 // b*256 + op, < 8192
    int k4 = (i & 255) * 4;
    int b = row >> 8, op = row & 255;
    const size_t base = (size_t)(b * CHART_ROWS + op) * 2048;
    const f32x4 vh = *(const f32x4*)(chart + base + 1024 + k4);
    const f32x4 vc = *(const f32x4*)(chart + base + k4);
    u16x4 oh = {f2bf(vh[0]), f2bf(vh[1]), f2bf(vh[2]), f2bf(vh[3])};
    h4v oc = {(_Float16)vc[0], (_Float16)vc[1], (_Float16)vc[2], (_Float16)vc[3]};
    *(u16x4*)(chb + (size_t)row * 1024 + k4) = oh;
    *(h4v*)(chc + (size_t)row * 1024 + k4) = oc;
    __builtin_nontemporal_store(vc, (f32x4*)(out + base + k4));
    __builtin_nontemporal_store(vh, (f32x4*)(out + base + 1024 + k4));
  }
}

// ---- P[bgh][2048 rows][5120] = chb-rows @ U-half (+bias*scale on half0)
// 256x256 tile, BK=64, 8 waves (2Mx4N), 8-phase double-buffered pipeline.
#define LOAD_A(BUFO, MH) do { \
  _Pragma("unroll") \
  for (int i_ = 0; i_ < 4; ++i_) { \
    a[0][i_] = *(const short8*)(As + (BUFO) + am + (MH)*4096 + i_*1024 + sl0); \
    a[1][i_] = *(const short8*)(As + (BUFO) + am + (MH)*4096 + i_*1024 + sl1); \
  } } while (0)

#define LOAD_B(BUFO, NH, BR) do { \
  _Pragma("unroll") \
  for (int j_ = 0; j_ < 2; ++j_) { \
    BR[0][j_] = *(const short8*)(Bs + (BUFO) + bm + (NH)*2048 + j_*1024 + sl0); \
    BR[1][j_] = *(const short8*)(Bs + (BUFO) + bm + (NH)*2048 + j_*1024 + sl1); \
  } } while (0)

#define MFMA_Q(MH, NH, BR) do { \
  __builtin_amdgcn_s_setprio(1); \
  _Pragma("unroll") \
  for (int kk_ = 0; kk_ < 2; ++kk_) \
    _Pragma("unroll") \
    for (int i_ = 0; i_ < 4; ++i_) \
      _Pragma("unroll") \
      for (int j_ = 0; j_ < 2; ++j_) \
        acc[(MH)*4+i_][(NH)*2+j_] = __builtin_amdgcn_mfma_f32_16x16x32_bf16( \
            a[kk_][i_], BR[kk_][j_], acc[(MH)*4+i_][(NH)*2+j_], 0, 0, 0); \
  __builtin_amdgcn_s_setprio(0); } while (0)

__global__ __launch_bounds__(512, 2) void k_gemm_p(
    const u16* __restrict__ chb, const u16* __restrict__ Ubf,
    const float* __restrict__ bias, _Float16* __restrict__ P, int bgh_base)
{
  __shared__ u16 As[2 * 256 * 64];   // 64 KB: two K-tile buffers (halves stacked)
  __shared__ u16 Bs[2 * 256 * 64];   // 64 KB

  const int tid = threadIdx.x;
  const int wid = tid >> 6, lane = tid & 63;
  const int lane15 = lane & 15, quad = lane >> 4;
  const int wr = wid >> 2, wc = wid & 3;

  // XCD-aware bijective swizzle (nwg % 8 == 0 in both launch shapes)
  const int nwg = gridDim.x * gridDim.y;
  const int flat = blockIdx.y * gridDim.x + blockIdx.x;
  const int swz = (flat & 7) * (nwg >> 3) + (flat >> 3);
  const int bx = swz % 20;                 // N tile (0..19)
  const int by = swz / 20;
  const int bghl = by >> 3;                // local bgh slab in P
  const int bgh = bgh_base + bghl;
  const int bg = bgh >> 1, uhalf = bgh & 1;
  const int mtile = by & 7;

  // staging: half-tile = 128 rows x 64 cols bf16 = 16KB = 2 rounds x 512 thr x 16B
  const u16* aSrc[2]; const u16* bSrc[2]; int dOff[2];
#pragma unroll
  for (int rnd = 0; rnd < 2; ++rnd) {
    int idx = rnd * 512 + tid;
    int r = idx >> 3, s = idx & 7, c = s ^ (r & 7);
    aSrc[rnd] = chb + (size_t)(bg * 2048 + mtile * 256 + r) * 1024 + c * 8;
    bSrc[rnd] = Ubf + (size_t)(bx * 256 + r) * 2048 + uhalf * 1024 + c * 8;
    dOff[rnd] = idx * 8;                   // u16 units
  }
  auto STAGE_A = [&](int buf, int h, int T) {
#pragma unroll
    for (int rnd = 0; rnd < 2; ++rnd)
      async16(aSrc[rnd] + (size_t)h * 131072 + T * 64,
              As + buf * 16384 + h * 8192 + dOff[rnd]);
  };
  auto STAGE_B = [&](int buf, int h, int T) {
#pragma unroll
    for (int rnd = 0; rnd < 2; ++rnd)
      async16(bSrc[rnd] + (size_t)h * 262144 + T * 64,
              Bs + buf * 16384 + h * 8192 + dOff[rnd]);
  };

  // fragment read bases; m&7 == g&7 == lane15&7 (all tile offsets are mult of 8)
  const int sl0 = ((0 * 4 + quad) ^ (lane15 & 7)) * 8;   // kk=0 slot
  const int sl1 = ((1 * 4 + quad) ^ (lane15 & 7)) * 8;   // kk=1 slot
  const int am = (wr * 128 + lane15) * 64;   // + mh*4096 + i*1024
  const int bm = (wc * 64 + lane15) * 64;    // + nh*2048 + j*1024

  f32x4 acc[8][4];
#pragma unroll
  for (int m_ = 0; m_ < 8; ++m_)
#pragma unroll
    for (int n_ = 0; n_ < 4; ++n_) acc[m_][n_] = (f32x4){0.f, 0.f, 0.f, 0.f};

  short8 a[2][4], b0[2][2], b1[2][2];

  // prologue: tile0 fully + tile1 B-halves; tile1 A staged in iter0 p1/p2
  STAGE_B(0, 0, 0); STAGE_B(0, 1, 0); STAGE_A(0, 0, 0); STAGE_A(0, 1, 0);
  STAGE_B(1, 0, 1); STAGE_B(1, 1, 1);
  VMCNT4;                                  // tile0 landed (tile1-B in flight)
  BAR();

  for (int it = 0; it < 8; ++it) {
    const int T1 = 2 * it + 1, T2 = 2 * it + 2, T3 = 2 * it + 3;
    const bool e2 = (T2 < 16), e3 = (T3 < 16);
    // ---- phases 1-4: tile 2it from buf0 ----
    LOAD_A(0, 0); LOAD_B(0, 0, b0);
    STAGE_A(1, 0, T1);
    BAR(); MFMA_Q(0, 0, b0); BAR();

    LOAD_B(0, 1, b1);
    STAGE_A(1, 1, T1);
    BAR(); MFMA_Q(0, 1, b1); BAR();

    LOAD_A(0, 1);
    if (e2) STAGE_B(0, 0, T2);             // buf0 B free after phase 2
    BAR(); MFMA_Q(1, 0, b0); BAR();

    if (e2) STAGE_B(0, 1, T2);
    BAR(); MFMA_Q(1, 1, b1);
    if (e2) { VMCNT4; } else { VMCNT0; }   // tile 2it+1 fully landed
    BAR();
    // ---- phases 5-8: tile 2it+1 from buf1 ----
    LOAD_A(16384, 0); LOAD_B(16384, 0, b0);
    if (e2) STAGE_A(0, 0, T2);             // buf0 A free after phase 3
    BAR(); MFMA_Q(0, 0, b0); BAR();

    LOAD_B(16384, 1, b1);
    if (e2) STAGE_A(0, 1, T2);
    BAR(); MFMA_Q(0, 1, b1); BAR();

    LOAD_A(16384, 1);
    if (e3) STAGE_B(1, 0, T3);             // buf1 B free after phase 6
    BAR(); MFMA_Q(1, 0, b0); BAR();

    if (e3) STAGE_B(1, 1, T3);
    BAR(); MFMA_Q(1, 1, b1);
    if (e3) { VMCNT4; }                    // tile 2it+2 fully landed
    BAR();
  }

  // epilogue: bias (half0 only, pre-scaled) + fp16 CACHED store (P is
  // re-read ~16x by k_fused -- keep it in L2/LLC)
  float bb[4];
#pragma unroll
  for (int nt = 0; nt < 4; ++nt) {
    int g = bx * 256 + wc * 64 + nt * 16 + lane15;
    float sc = (g < 4096) ? -L2E : (2.0f * L2E);
    bb[nt] = (uhalf == 0) ? bias[g] * sc : 0.f;
  }
  _Float16* Pb = P + ((size_t)bghl * 2048 + mtile * 256 + wr * 128) * 5120
               + bx * 256 + wc * 64;
#pragma unroll
  for (int mt = 0; mt < 8; ++mt)
#pragma unroll
    for (int rg = 0; rg < 4; ++rg) {
      _Float16* pr = Pb + (size_t)(mt * 16 + quad * 4 + rg) * 5120;
#pragma unroll
      for (int nt = 0; nt < 4; ++nt)
        pr[nt * 16 + lane15] = (_Float16)(acc[mt][nt][rg] + bb[nt]);
    }
}

// ---- fused v6: sub-phased online softmax-combine, fully unrolled ----
// 4 waves x 8 rows. Phase A: all rows, cols [0,512); pending h in 32
// STATIC regs, pending c (f16) in wave's 8KB LDS slice (aliased with
// merge buffer; wave-private, in-wave lgkmcnt orders it). Phase B: all
// rows, cols [512,1024); completes dot/nn -> e,w; weights live+pending.
// All pending arrays indexed by compile-time rr (full unroll, rule #20).
__global__ __launch_bounds__(256, 2) void k_fused(
    const _Float16* __restrict__ chc, const _Float16* __restrict__ P,
    const int* __restrict__ ops, const float* __restrict__ eu,
    float* __restrict__ out, int bg0)
{
  __shared__ float rS[4 * 2048];   // 32 KB; during phases: per-wave cPend slices
  __shared__ float sS[4];

  const int tid = threadIdx.x;
  const int wave = tid >> 6, lane = tid & 63;
  const int flat = blockIdx.x;
  const int b_local = flat & 7;     // XCD-affine: same-XCD blocks share b
  const int idx = flat >> 3;
  const int step = idx & 127;
  const int bgl = idx >> 7;         // slab index within P
  const int b = (bg0 + bgl) * 8 + b_local;
  const size_t HSLAB = (size_t)2048 * 5120;
  const _Float16* Pl = P + (size_t)(2 * bgl) * HSLAB;
  _Float16* cP = (_Float16*)rS + wave * 4096;   // wave-private 8KB = [8 rows][512] f16

  // energy_u: f32 for unorm, f16 pairs for fdot2
  float uf[2][8];
#pragma unroll
  for (int sub = 0; sub < 2; ++sub) {
    *(f32x4*)&uf[sub][0] = *(const f32x4*)(eu + sub * 512 + lane * 8);
    *(f32x4*)&uf[sub][4] = *(const f32x4*)(eu + sub * 512 + lane * 8 + 4);
  }
  float part = 0.f;
#pragma unroll
  for (int sub = 0; sub < 2; ++sub)
#pragma unroll
    for (int j = 0; j < 8; ++j) part += uf[sub][j] * uf[sub][j];
#pragma unroll
  for (int m = 1; m < 64; m <<= 1) part += __shfl_xor(part, m, 64);
  const float unorm = fmaxf(sqrtf(part), 1e-8f);
  h2v uu2[2][4];
#pragma unroll
  for (int sub = 0; sub < 2; ++sub)
#pragma unroll
    for (int p = 0; p < 4; ++p)
      uu2[sub][p] = (h2v){(_Float16)uf[sub][2 * p], (_Float16)uf[sub][2 * p + 1]};

  const h2v one2 = {(_Float16)1.0f, (_Float16)1.0f};
  const h2v m2h  = {(_Float16)(-2.0f), (_Float16)(-2.0f)};
  const h2v k2c  = {(_Float16)(2.0f * L2E), (_Float16)(2.0f * L2E)};

  h2v hP[8][4];                 // pending sub0 h (32 VGPRs, static indices)
  float dotP[8], nnP[8];        // partial reductions (16 VGPRs, static indices)

  // ---- Phase A: all 8 rows, cols [0,512) ----
#pragma unroll
  for (int rr = 0; rr < 8; ++rr) {
    const int a = wave * 8 + rr;
    const long opflat = (((long)step * 32 + b) * 32 + a) * 2;
    const int opL = ops[opflat], opR = ops[opflat + 1];
    const int cb = lane * 8;
    const _Float16* PLp = Pl + (size_t)(b_local * 256 + opL) * 5120 + cb;
    const _Float16* PRp = Pl + HSLAB + (size_t)(b_local * 256 + opR) * 5120 + cb;
    h2v pr2[5][4];
#pragma unroll
    for (int q = 0; q < 5; ++q) {
      h8 t8 = *(const h8*)(PLp + q * 1024) + *(const h8*)(PRp + q * 1024);
      *(h8*)&pr2[q][0] = t8;
    }
    h2v cl2[4], cr2[4];
    *(h8*)&cl2[0] = *(const h8*)(chc + (size_t)(b * 256 + opL) * 1024 + cb);
    *(h8*)&cr2[0] = *(const h8*)(chc + (size_t)(b * 256 + opR) * 1024 + cb);
    float dot = 0.f, nn = 0.f;
    h2v cv4[4];
#pragma unroll
    for (int p = 0; p < 4; ++p) {
      h2v sI = pk_rcp(one2 + pk_exp2(pr2[0][p]));   // args pre-scaled -log2e
      h2v sL = pk_rcp(one2 + pk_exp2(pr2[1][p]));
      h2v sR = pk_rcp(one2 + pk_exp2(pr2[2][p]));
      h2v sO = pk_rcp(one2 + pk_exp2(pr2[3][p]));
      h2v rU = pk_rcp(one2 + pk_exp2(pr2[4][p]));   // pre-scaled +2log2e
      h2v tU = one2 + m2h * rU;                     // tanh(u)
      h2v c2 = sL * cl2[p] + sR * cr2[p] + sI * tU;
      h2v rC = pk_rcp(one2 + pk_exp2(c2 * k2c));
      h2v tC = one2 + m2h * rC;                     // tanh(c)
      h2v hx = sO * tC;
      cv4[p] = c2; hP[rr][p] = hx;
      dot = fdot2a(hx, uu2[0][p], dot);
      nn  = fdot2a(hx, hx, nn);
    }
    *(h8*)(cP + rr * 512 + lane * 8) = *(h8*)&cv4[0];   // pending c -> LDS (b128)
    dotP[rr] = dot; nnP[rr] = nn;
  }

  // Sc/Sh live only from here (keeps Phase-A register pressure low)
  float Sc[2][8], Sh[2][8];
#pragma unroll
  for (int sub = 0; sub < 2; ++sub)
#pragma unroll
    for (int j = 0; j < 8; ++j) { Sc[sub][j] = 0.f; Sh[sub][j] = 0.f; }
  float Ssum = 0.f;

  // ---- Phase B: all 8 rows, cols [512,1024); complete + weight ----
#pragma unroll
  for (int rr = 0; rr < 8; ++rr) {
    const int a = wave * 8 + rr;
    const long opflat = (((long)step * 32 + b) * 32 + a) * 2;
    const int opL = ops[opflat], opR = ops[opflat + 1];
    const int cb = 512 + lane * 8;
    const _Float16* PLp = Pl + (size_t)(b_local * 256 + opL) * 5120 + cb;
    const _Float16* PRp = Pl + HSLAB + (size_t)(b_local * 256 + opR) * 5120 + cb;
    h2v pr2[5][4];
#pragma unroll
    for (int q = 0; q < 5; ++q) {
      h8 t8 = *(const h8*)(PLp + q * 1024) + *(const h8*)(PRp + q * 1024);
      *(h8*)&pr2[q][0] = t8;
    }
    h2v cl2[4], cr2[4];
    *(h8*)&cl2[0] = *(const h8*)(chc + (size_t)(b * 256 + opL) * 1024 + cb);
    *(h8*)&cr2[0] = *(const h8*)(chc + (size_t)(b * 256 + opR) * 1024 + cb);
    float dot = dotP[rr], nn = nnP[rr];
    h2v cv1[4], hv1[4];
#pragma unroll
    for (int p = 0; p < 4; ++p) {
      h2v sI = pk_rcp(one2 + pk_exp2(pr2[0][p]));
      h2v sL = pk_rcp(one2 + pk_exp2(pr2[1][p]));
      h2v sR = pk_rcp(one2 + pk_exp2(pr2[2][p]));
      h2v sO = pk_rcp(one2 + pk_exp2(pr2[3][p]));
      h2v rU = pk_rcp(one2 + pk_exp2(pr2[4][p]));
      h2v tU = one2 + m2h * rU;
      h2v c2 = sL * cl2[p] + sR * cr2[p] + sI * tU;
      h2v rC = pk_rcp(one2 + pk_exp2(c2 * k2c));
      h2v tC = one2 + m2h * rC;
      h2v hx = sO * tC;
      cv1[p] = c2; hv1[p] = hx;
      dot = fdot2a(hx, uu2[1][p], dot);
      nn  = fdot2a(hx, hx, nn);
    }
#pragma unroll
    for (int m = 1; m < 64; m <<= 1) {
      dot += __shfl_xor(dot, m, 64);
      nn  += __shfl_xor(nn, m, 64);
    }
    const float e = dot / (unorm * fmaxf(sqrtf(nn), 1e-8f));
    const float w = __builtin_amdgcn_exp2f(e * L2E);        // exp(e), e in [-1,1]
    Ssum += w;
    h2v cp4[4];
    *(h8*)&cp4[0] = *(const h8*)(cP + rr * 512 + lane * 8);  // pending c back
#pragma unroll
    for (int p = 0; p < 4; ++p) {
      Sc[0][2 * p]     += w * (float)cp4[p][0];
      Sc[0][2 * p + 1] += w * (float)cp4[p][1];
      Sh[0][2 * p]     += w * (float)hP[rr][p][0];
      Sh[0][2 * p + 1] += w * (float)hP[rr][p][1];
      Sc[1][2 * p]     += w * (float)cv1[p][0];
      Sc[1][2 * p + 1] += w * (float)cv1[p][1];
      Sh[1][2 * p]     += w * (float)hv1[p][0];
      Sh[1][2 * p + 1] += w * (float)hv1[p][1];
    }
  }

  // ---- 4-wave merge through rS (cPend fully consumed; wave-private alias) ----
  if (lane == 0) sS[wave] = Ssum;
#pragma unroll
  for (int sub = 0; sub < 2; ++sub) {
    const int cb = sub * 512 + lane * 8;
    *(f32x4*)&rS[wave * 2048 + cb]            = *(f32x4*)&Sc[sub][0];
    *(f32x4*)&rS[wave * 2048 + cb + 4]        = *(f32x4*)&Sc[sub][4];
    *(f32x4*)&rS[wave * 2048 + 1024 + cb]     = *(f32x4*)&Sh[sub][0];
    *(f32x4*)&rS[wave * 2048 + 1024 + cb + 4] = *(f32x4*)&Sh[sub][4];
  }
  __syncthreads();

  const float inv = 1.0f / (sS[0] + sS[1] + sS[2] + sS[3]);
  float* orow = out + ((size_t)b * CHART_ROWS + 256 + step) * 2048;
#pragma unroll
  for (int half = 0; half < 2; ++half) {     // 0: c cols, 1: h cols
#pragma unroll
    for (int sub = 0; sub < 2; ++sub) {
      const int cb = sub * 512 + lane * 8;
      const int off = half * 1024 + cb;
      float s0 = 0.f, s1 = 0.f, s2 = 0.f, s3 = 0.f;
      float s4 = 0.f, s5 = 0.f, s6 = 0.f, s7 = 0.f;
#pragma unroll
      for (int w8 = 0; w8 < 4; ++w8) {
        const f32x4 v0 = *(const f32x4*)&rS[w8 * 2048 + off];
        const f32x4 v1 = *(const f32x4*)&rS[w8 * 2048 + off + 4];
        s0 += v0[0]; s1 += v0[1]; s2 += v0[2]; s3 += v0[3];
        s4 += v1[0]; s5 += v1[1]; s6 += v1[2]; s7 += v1[3];
      }
      __builtin_nontemporal_store(
          (f32x4){s0 * inv, s1 * inv, s2 * inv, s3 * inv}, (f32x4*)(orow + off));
      __builtin_nontemporal_store(
          (f32x4){s4 * inv, s5 * inv, s6 * inv, s7 * inv}, (f32x4*)(orow + off + 4));
    }
  }
}

extern "C" void kernel_launch(void* const* d_in, const int* in_sizes, int n_in,
                              void* d_out, int out_size, void* d_ws, size_t ws_size,
                              hipStream_t stream) {
  (void)in_sizes; (void)n_in; (void)out_size;
  const float* chart = (const float*)d_in[0];
  const int*   ops   = (const int*)d_in[1];
  // d_in[2] = start_index (256, hard-coded)
  const float* U     = (const float*)d_in[3];
  const float* bias  = (const float*)d_in[4];
  const float* eu    = (const float*)d_in[5];
  float* out = (float*)d_out;
  char* ws = (char*)d_ws;

  u16*      Ubf = (u16*)ws;                       // 20,971,520 B
  u16*      chb = (u16*)(ws + 20971520);          // 16,777,216 B
  _Float16* chc = (_Float16*)(ws + 37748736);     // 16,777,216 B
  _Float16* P   = (_Float16*)(ws + 54525952);     // big: 167,772,160 B (8 slabs)
                                                  // small: 41,943,040 B (2 slabs)
  const size_t SLAB = (size_t)2048 * 5120;        // _Float16 per slab
  const bool big = ws_size >= (size_t)54525952 + 8 * SLAB * 2;

  k_cvt<<<18432, 256, 0, stream>>>((const f32x4*)U, Ubf, chart, chb, chc, out);

  if (big) {
    // 1280 tiles (20 bx x 8 bgh x 8 mt), 5 exact rounds of 256 blocks
    k_gemm_p<<<dim3(20, 64), 512, 0, stream>>>(chb, Ubf, bias, P, 0);
    // single fused dispatch over all bg (4096 blocks x 256 thr)
    k_fused<<<4096, 256, 0, stream>>>(chc, P, ops, eu, out, 0);
  } else {
    for (int bg = 0; bg < 4; ++bg) {
      k_gemm_p<<<dim3(20, 16), 512, 0, stream>>>(chb, Ubf, bias, P, 2 * bg);
      k_fused<<<1024, 256, 0, stream>>>(chc, P, ops, eu, out, bg);
    }
  }
}